// Round 1
// baseline (352.179 us; speedup 1.0000x reference)
//
#include <hip/hip_runtime.h>

typedef unsigned short ushort_t;
typedef __attribute__((ext_vector_type(8))) __bf16 bf16x8;
typedef __attribute__((ext_vector_type(4))) float f32x4;

// async global->LDS, 16B per lane. LDS dest must be wave-uniform base; HW writes
// lane i's 16B at base + i*16 (guide §5, m97/m104).
#define GLOAD_LDS16(gp, lp)                                                              \
  __builtin_amdgcn_global_load_lds(                                                     \
      (const __attribute__((address_space(1))) unsigned int*)(gp),                      \
      (__attribute__((address_space(3))) unsigned int*)(lp), 16, 0, 0)

__device__ __forceinline__ ushort_t f2bf(float f) {
  unsigned u = __builtin_bit_cast(unsigned, f);
  u += 0x7fffu + ((u >> 16) & 1u);   // RNE
  return (ushort_t)(u >> 16);
}
__device__ __forceinline__ float bf2f(ushort_t h) {
  return __builtin_bit_cast(float, (unsigned)h << 16);
}

// ---------------- pack: f32 -> bf16 (vectorized, G13) ----------------
__global__ __launch_bounds__(256) void k_f32_to_bf16(const float* __restrict__ src,
                                                     ushort_t* __restrict__ dst, int n) {
  int i = (blockIdx.x * 256 + threadIdx.x) * 4;
  if (i >= n) return;
  float4 v = *reinterpret_cast<const float4*>(src + i);
  ushort4 o;
  o.x = f2bf(v.x); o.y = f2bf(v.y); o.z = f2bf(v.z); o.w = f2bf(v.w);
  *reinterpret_cast<ushort4*>(dst + i) = o;
}

// ---------------- GEMM: C[m][n] = sum_k A[m][k]*Bw[n][k] + bias[n] (+relu if n<relu_lim)
// m97-style 128x128 tile, BK=32, 4 waves (2x2), 16x16x32 bf16 MFMA.
template <bool OUT_F32>
__global__ __launch_bounds__(256) void k_gemm_bt(const ushort_t* __restrict__ A, int lda,
                                                 const ushort_t* __restrict__ Bw, int ldb,
                                                 const float* __restrict__ bias, int relu_lim,
                                                 void* __restrict__ Cout, int ldc, int K) {
  __shared__ ushort_t As[128 * 32];
  __shared__ ushort_t Bs[128 * 32];
  const int t = threadIdx.x;
  const int lane = t & 63;
  const int w = t >> 6;
  const int wr = w >> 1, wc = w & 1;
  const long rowBase = (long)blockIdx.y * 128;
  const long colBase = (long)blockIdx.x * 128;

  const ushort_t* Ap = A + rowBase * lda;
  const ushort_t* Bp = Bw + colBase * ldb;

  // staging chunk ids: chunk c covers row c>>2, cols (c&3)*8..+8 of the [128][32] tile
  const int c0 = w * 128 + lane;
  const int c1 = c0 + 64;
  const int r0 = c0 >> 2, q0 = (c0 & 3) * 8;
  const int r1 = c1 >> 2, q1 = (c1 & 3) * 8;

  f32x4 zero = {0.f, 0.f, 0.f, 0.f};
  f32x4 acc[4][4];
#pragma unroll
  for (int mf = 0; mf < 4; mf++)
#pragma unroll
    for (int nf = 0; nf < 4; nf++) acc[mf][nf] = zero;

  const int arow = wr * 64 + (lane & 15);
  const int brow = wc * 64 + (lane & 15);
  const int kcol = (lane >> 4) * 8;

  for (int kt = 0; kt < K; kt += 32) {
    GLOAD_LDS16(Ap + (long)r0 * lda + kt + q0, &As[w * 1024]);
    GLOAD_LDS16(Ap + (long)r1 * lda + kt + q1, &As[w * 1024 + 512]);
    GLOAD_LDS16(Bp + (long)r0 * ldb + kt + q0, &Bs[w * 1024]);
    GLOAD_LDS16(Bp + (long)r1 * ldb + kt + q1, &Bs[w * 1024 + 512]);
    __syncthreads();

    bf16x8 af[4], bfr[4];
#pragma unroll
    for (int mf = 0; mf < 4; mf++)
      af[mf] = *reinterpret_cast<const bf16x8*>(&As[(arow + mf * 16) * 32 + kcol]);
#pragma unroll
    for (int nf = 0; nf < 4; nf++)
      bfr[nf] = *reinterpret_cast<const bf16x8*>(&Bs[(brow + nf * 16) * 32 + kcol]);
#pragma unroll
    for (int mf = 0; mf < 4; mf++)
#pragma unroll
      for (int nf = 0; nf < 4; nf++)
        acc[mf][nf] = __builtin_amdgcn_mfma_f32_16x16x32_bf16(af[mf], bfr[nf], acc[mf][nf], 0, 0, 0);
    __syncthreads();
  }

  // epilogue: C/D layout col=lane&15, row=(lane>>4)*4+r (m89-verified)
  const int colLoc = wc * 64 + (lane & 15);
  const int rowQ = (lane >> 4) * 4;
#pragma unroll
  for (int nf = 0; nf < 4; nf++) {
    const int col = (int)colBase + colLoc + nf * 16;
    const float bv = bias[col];
    const bool doRelu = col < relu_lim;
#pragma unroll
    for (int mf = 0; mf < 4; mf++) {
      const long row = rowBase + wr * 64 + mf * 16 + rowQ;
#pragma unroll
      for (int r = 0; r < 4; r++) {
        float v = acc[mf][nf][r] + bv;
        if (doRelu) v = fmaxf(v, 0.f);
        if (OUT_F32)
          ((float*)Cout)[(row + r) * (long)ldc + col] = v;
        else
          ((ushort_t*)Cout)[(row + r) * (long)ldc + col] = f2bf(v);
      }
    }
  }
}

// ---------------- KV state: partial[chunk][b*16+h][d][e] = sum_{s in chunk} k[b,s,h,d]*v[b,s,h,e]
// qkv layout: [m][3072], q at 0, k at 1024, v at 2048. Deterministic 2-stage (no float atomics).
__global__ __launch_bounds__(256) void k_kv_partial(const ushort_t* __restrict__ qkv,
                                                    float* __restrict__ partial) {
  const int bh = blockIdx.x;     // 0..63
  const int chunk = blockIdx.y;  // 0..15
  const int b = bh >> 4, h = bh & 15;
  const int t = threadIdx.x;
  const int d = t >> 2, e0 = (t & 3) * 16;
  __shared__ float kk[8][64];
  __shared__ float vv[8][64];
  float acc[16];
#pragma unroll
  for (int j = 0; j < 16; j++) acc[j] = 0.f;

  const long rowbase = (long)b * 4096 + (long)chunk * 256;
  for (int s8 = 0; s8 < 32; s8++) {
    __syncthreads();
#pragma unroll
    for (int rep = 0; rep < 2; rep++) {
      int lin = rep * 256 + t;  // 0..511 = 8 rows x 64 cols
      int ss = lin >> 6, c = lin & 63;
      long m = rowbase + s8 * 8 + ss;
      kk[ss][c] = bf2f(qkv[m * 3072 + 1024 + h * 64 + c]);
      vv[ss][c] = bf2f(qkv[m * 3072 + 2048 + h * 64 + c]);
    }
    __syncthreads();
#pragma unroll
    for (int ss = 0; ss < 8; ss++) {
      float kd = kk[ss][d];
#pragma unroll
      for (int j = 0; j < 16; j++) acc[j] = fmaf(kd, vv[ss][e0 + j], acc[j]);
    }
  }
  float* dst = partial + ((long)chunk * 64 + bh) * 4096 + d * 64 + e0;
#pragma unroll
  for (int j4 = 0; j4 < 4; j4++) {
    float4 o = make_float4(acc[j4 * 4], acc[j4 * 4 + 1], acc[j4 * 4 + 2], acc[j4 * 4 + 3]);
    *reinterpret_cast<float4*>(dst + j4 * 4) = o;
  }
}

__global__ __launch_bounds__(256) void k_kv_reduce(const float* __restrict__ partial,
                                                   float* __restrict__ kv) {
  int i = blockIdx.x * 256 + threadIdx.x;  // 0..262143
  float s = 0.f;
#pragma unroll
  for (int c = 0; c < 16; c++) s += partial[(long)c * 262144 + i];
  kv[i] = s;
}

// ---------------- readout: attn[m][h*64+e] = sum_d q[m][h*64+d] * kv[b,h,d,e]
// writes bf16 IN PLACE over the q region of qkv (row-disjoint per thread -> safe).
__global__ __launch_bounds__(256) void k_readout(ushort_t* __restrict__ qkv,
                                                 const float* __restrict__ kv) {
  const int m0 = blockIdx.x * 16;
  const int b = m0 >> 12;
  const int t = threadIdx.x;
  const int ml = t >> 4, e0 = (t & 15) * 4;
  __shared__ float kvs[64][64];
  __shared__ float qs[16][65];  // +1 pad: avoid 16-way bank conflict on qs[ml][d]

  for (int h = 0; h < 16; h++) {
    __syncthreads();
    const float* kvsrc = kv + ((long)(b * 16 + h)) * 4096;
#pragma unroll
    for (int r = 0; r < 16; r++) {
      int lin = r * 256 + t;
      kvs[lin >> 6][lin & 63] = kvsrc[lin];
    }
#pragma unroll
    for (int r = 0; r < 4; r++) {
      int lin = r * 256 + t;
      qs[lin >> 6][lin & 63] = bf2f(qkv[(long)(m0 + (lin >> 6)) * 3072 + h * 64 + (lin & 63)]);
    }
    __syncthreads();
    float a0 = 0.f, a1 = 0.f, a2 = 0.f, a3 = 0.f;
#pragma unroll
    for (int dd = 0; dd < 64; dd++) {
      float qd = qs[ml][dd];
      const float4 kr = *reinterpret_cast<const float4*>(&kvs[dd][e0]);
      a0 = fmaf(qd, kr.x, a0);
      a1 = fmaf(qd, kr.y, a1);
      a2 = fmaf(qd, kr.z, a2);
      a3 = fmaf(qd, kr.w, a3);
    }
    ushort4 o;
    o.x = f2bf(a0); o.y = f2bf(a1); o.z = f2bf(a2); o.w = f2bf(a3);
    *reinterpret_cast<ushort4*>(&qkv[(long)(m0 + ml) * 3072 + h * 64 + e0]) = o;
  }
}

extern "C" void kernel_launch(void* const* d_in, const int* in_sizes, int n_in, void* d_out,
                              int out_size, void* d_ws, size_t ws_size, hipStream_t stream) {
  const float* x   = (const float*)d_in[0];
  const float* q_w = (const float*)d_in[1];
  const float* q_b = (const float*)d_in[2];
  const float* k_w = (const float*)d_in[3];
  const float* k_b = (const float*)d_in[4];
  const float* v_w = (const float*)d_in[5];
  const float* v_b = (const float*)d_in[6];
  const float* o_w = (const float*)d_in[7];
  const float* o_b = (const float*)d_in[8];
  float* out = (float*)d_out;

  const int D = 1024, M = 16384;
  char* ws = (char*)d_ws;
  // layout (bytes):
  ushort_t* xb    = (ushort_t*)(ws);              // 33,554,432  x as bf16
  ushort_t* wqkv  = (ushort_t*)(ws + 33554432);   //  6,291,456  [q_w;k_w;v_w] bf16
  ushort_t* owb   = (ushort_t*)(ws + 39845888);   //  2,097,152  o_w bf16
  float*    biasq = (float*)(ws + 41943040);      //     12,288  [q_b;k_b;v_b]
  ushort_t* qkv   = (ushort_t*)(ws + 41955328);   // 100,663,296 [M][3072] bf16 (q later overwritten by attn)
  // xb region recycled after GEMM1:
  float* kvbuf   = (float*)(ws);                  //  1,048,576  [B*H][64][64]
  float* partial = (float*)(ws + 1048576);        // 16,777,216  [16][B*H][64][64]

  // pack inputs to bf16
  k_f32_to_bf16<<<16384, 256, 0, stream>>>(x, xb, M * D);
  k_f32_to_bf16<<<1024, 256, 0, stream>>>(q_w, wqkv, D * D);
  k_f32_to_bf16<<<1024, 256, 0, stream>>>(k_w, wqkv + D * D, D * D);
  k_f32_to_bf16<<<1024, 256, 0, stream>>>(v_w, wqkv + 2 * D * D, D * D);
  k_f32_to_bf16<<<1024, 256, 0, stream>>>(o_w, owb, D * D);
  hipMemcpyAsync(biasq, q_b, D * sizeof(float), hipMemcpyDeviceToDevice, stream);
  hipMemcpyAsync(biasq + D, k_b, D * sizeof(float), hipMemcpyDeviceToDevice, stream);
  hipMemcpyAsync(biasq + 2 * D, v_b, D * sizeof(float), hipMemcpyDeviceToDevice, stream);

  // QKV projection: [16384 x 1024] x [3072 x 1024]^T, bias + relu on q,k cols (<2048)
  k_gemm_bt<false><<<dim3(24, 128), 256, 0, stream>>>(xb, 1024, wqkv, 1024, biasq, 2048,
                                                      qkv, 3072, 1024);
  // KV state (two-stage deterministic reduction over S)
  k_kv_partial<<<dim3(64, 16), 256, 0, stream>>>(qkv, partial);
  k_kv_reduce<<<1024, 256, 0, stream>>>(partial, kvbuf);
  // Q readout, in place over q region
  k_readout<<<1024, 256, 0, stream>>>(qkv, kvbuf);
  // O projection: [16384 x 1024(attn)] x [1024 x 1024]^T + o_b -> f32 out
  k_gemm_bt<true><<<dim3(8, 128), 256, 0, stream>>>(qkv, 3072, owb, 1024, o_b, 0,
                                                    out, 1024, 1024);
}

// Round 2
// 346.358 us; speedup vs baseline: 1.0168x; 1.0168x over previous
//
#include <hip/hip_runtime.h>

typedef unsigned short ushort_t;
typedef __attribute__((ext_vector_type(8))) __bf16 bf16x8;
typedef __attribute__((ext_vector_type(4))) float f32x4;

// async global->LDS, 16B per lane. LDS dest must be wave-uniform base; HW writes
// lane i's 16B at base + i*16 (guide §5, m97/m104).
#define GLOAD_LDS16(gp, lp)                                                              \
  __builtin_amdgcn_global_load_lds(                                                     \
      (const __attribute__((address_space(1))) unsigned int*)(gp),                      \
      (__attribute__((address_space(3))) unsigned int*)(lp), 16, 0, 0)

__device__ __forceinline__ ushort_t f2bf(float f) {
  unsigned u = __builtin_bit_cast(unsigned, f);
  u += 0x7fffu + ((u >> 16) & 1u);   // RNE
  return (ushort_t)(u >> 16);
}
__device__ __forceinline__ float bf2f(ushort_t h) {
  return __builtin_bit_cast(float, (unsigned)h << 16);
}

// ---------------- pack: f32 -> bf16 (vectorized, G13) ----------------
__global__ __launch_bounds__(256) void k_f32_to_bf16(const float* __restrict__ src,
                                                     ushort_t* __restrict__ dst, int n) {
  int i = (blockIdx.x * 256 + threadIdx.x) * 4;
  if (i >= n) return;
  float4 v = *reinterpret_cast<const float4*>(src + i);
  ushort4 o;
  o.x = f2bf(v.x); o.y = f2bf(v.y); o.z = f2bf(v.z); o.w = f2bf(v.w);
  *reinterpret_cast<ushort4*>(dst + i) = o;
}

// pack all four weight matrices (q,k,v,o each 1024x1024 f32) into contiguous bf16
__global__ __launch_bounds__(256) void k_pack_w4(const float* __restrict__ w0,
                                                 const float* __restrict__ w1,
                                                 const float* __restrict__ w2,
                                                 const float* __restrict__ w3,
                                                 ushort_t* __restrict__ dst) {
  const int blk = blockIdx.x;          // 0..4095
  const int wsel = blk >> 10;
  const float* src = wsel == 0 ? w0 : wsel == 1 ? w1 : wsel == 2 ? w2 : w3;
  const int off = (blk & 1023) * 1024 + threadIdx.x * 4;
  float4 v = *reinterpret_cast<const float4*>(src + off);
  ushort4 o;
  o.x = f2bf(v.x); o.y = f2bf(v.y); o.z = f2bf(v.z); o.w = f2bf(v.w);
  *reinterpret_cast<ushort4*>(dst + wsel * 1048576 + off) = o;
}

// ---------------- GEMM: C[m][n] = sum_k A[m][k]*Bw[n][k] + bias[n] (+relu if n<relu_lim)
// m97-style 128x128 tile, BK=32, 4 waves (2x2), 16x16x32 bf16 MFMA.
template <bool OUT_F32>
__global__ __launch_bounds__(256) void k_gemm_bt(const ushort_t* __restrict__ A, int lda,
                                                 const ushort_t* __restrict__ Bw, int ldb,
                                                 const float* __restrict__ bias, int relu_lim,
                                                 void* __restrict__ Cout, int ldc, int K) {
  __shared__ ushort_t As[128 * 32];
  __shared__ ushort_t Bs[128 * 32];
  const int t = threadIdx.x;
  const int lane = t & 63;
  const int w = t >> 6;
  const int wr = w >> 1, wc = w & 1;
  const long rowBase = (long)blockIdx.y * 128;
  const long colBase = (long)blockIdx.x * 128;

  const ushort_t* Ap = A + rowBase * lda;
  const ushort_t* Bp = Bw + colBase * ldb;

  // staging chunk ids: chunk c covers row c>>2, cols (c&3)*8..+8 of the [128][32] tile
  const int c0 = w * 128 + lane;
  const int c1 = c0 + 64;
  const int r0 = c0 >> 2, q0 = (c0 & 3) * 8;
  const int r1 = c1 >> 2, q1 = (c1 & 3) * 8;

  f32x4 zero = {0.f, 0.f, 0.f, 0.f};
  f32x4 acc[4][4];
#pragma unroll
  for (int mf = 0; mf < 4; mf++)
#pragma unroll
    for (int nf = 0; nf < 4; nf++) acc[mf][nf] = zero;

  const int arow = wr * 64 + (lane & 15);
  const int brow = wc * 64 + (lane & 15);
  const int kcol = (lane >> 4) * 8;

  for (int kt = 0; kt < K; kt += 32) {
    GLOAD_LDS16(Ap + (long)r0 * lda + kt + q0, &As[w * 1024]);
    GLOAD_LDS16(Ap + (long)r1 * lda + kt + q1, &As[w * 1024 + 512]);
    GLOAD_LDS16(Bp + (long)r0 * ldb + kt + q0, &Bs[w * 1024]);
    GLOAD_LDS16(Bp + (long)r1 * ldb + kt + q1, &Bs[w * 1024 + 512]);
    __syncthreads();

    bf16x8 af[4], bfr[4];
#pragma unroll
    for (int mf = 0; mf < 4; mf++)
      af[mf] = *reinterpret_cast<const bf16x8*>(&As[(arow + mf * 16) * 32 + kcol]);
#pragma unroll
    for (int nf = 0; nf < 4; nf++)
      bfr[nf] = *reinterpret_cast<const bf16x8*>(&Bs[(brow + nf * 16) * 32 + kcol]);
#pragma unroll
    for (int mf = 0; mf < 4; mf++)
#pragma unroll
      for (int nf = 0; nf < 4; nf++)
        acc[mf][nf] = __builtin_amdgcn_mfma_f32_16x16x32_bf16(af[mf], bfr[nf], acc[mf][nf], 0, 0, 0);
    __syncthreads();
  }

  // epilogue: C/D layout col=lane&15, row=(lane>>4)*4+r (m89-verified)
  const int colLoc = wc * 64 + (lane & 15);
  const int rowQ = (lane >> 4) * 4;
#pragma unroll
  for (int nf = 0; nf < 4; nf++) {
    const int col = (int)colBase + colLoc + nf * 16;
    const float bv = bias[col];
    const bool doRelu = col < relu_lim;
#pragma unroll
    for (int mf = 0; mf < 4; mf++) {
      const long row = rowBase + wr * 64 + mf * 16 + rowQ;
#pragma unroll
      for (int r = 0; r < 4; r++) {
        float v = acc[mf][nf][r] + bv;
        if (doRelu) v = fmaxf(v, 0.f);
        if (OUT_F32)
          ((float*)Cout)[(row + r) * (long)ldc + col] = v;
        else
          ((ushort_t*)Cout)[(row + r) * (long)ldc + col] = f2bf(v);
      }
    }
  }
}

// ---------------- KV state partials: partial[chunk][bh][d][e] = sum_{s in 128-chunk} k*v
// 1-wave blocks, 4d x 16e register blocking (LDS bytes/flop 4x lower than 1x16).
__global__ __launch_bounds__(64) void k_kv_partial(const ushort_t* __restrict__ qkv,
                                                   float* __restrict__ partial) {
  const int bh = blockIdx.x;     // 0..63
  const int chunk = blockIdx.y;  // 0..31
  const int b = bh >> 4, h = bh & 15;
  const int t = threadIdx.x;     // 0..63
  const int d0 = (t >> 2) * 4;
  const int e0 = (t & 3) * 16;
  __shared__ float kk[16][64];
  __shared__ float vv[16][64];
  float acc[4][16];
#pragma unroll
  for (int di = 0; di < 4; di++)
#pragma unroll
    for (int j = 0; j < 16; j++) acc[di][j] = 0.f;

  const long rowbase = (long)b * 4096 + (long)chunk * 128;
  for (int it = 0; it < 8; it++) {
    __syncthreads();
#pragma unroll
    for (int rep = 0; rep < 4; rep++) {
      int idx = rep * 64 + t;  // 0..255 = 16 rows x 16 col-quads
      int row = idx >> 4, c4 = (idx & 15) * 4;
      long m = rowbase + it * 16 + row;
      ushort4 kr = *reinterpret_cast<const ushort4*>(&qkv[m * 3072 + 1024 + h * 64 + c4]);
      ushort4 vr = *reinterpret_cast<const ushort4*>(&qkv[m * 3072 + 2048 + h * 64 + c4]);
      float4 kf = make_float4(bf2f(kr.x), bf2f(kr.y), bf2f(kr.z), bf2f(kr.w));
      float4 vf = make_float4(bf2f(vr.x), bf2f(vr.y), bf2f(vr.z), bf2f(vr.w));
      *reinterpret_cast<float4*>(&kk[row][c4]) = kf;
      *reinterpret_cast<float4*>(&vv[row][c4]) = vf;
    }
    __syncthreads();
#pragma unroll
    for (int ss = 0; ss < 16; ss++) {
      const float4 kq = *reinterpret_cast<const float4*>(&kk[ss][d0]);
#pragma unroll
      for (int jj = 0; jj < 4; jj++) {
        const float4 vq = *reinterpret_cast<const float4*>(&vv[ss][e0 + jj * 4]);
        acc[0][jj * 4 + 0] = fmaf(kq.x, vq.x, acc[0][jj * 4 + 0]);
        acc[0][jj * 4 + 1] = fmaf(kq.x, vq.y, acc[0][jj * 4 + 1]);
        acc[0][jj * 4 + 2] = fmaf(kq.x, vq.z, acc[0][jj * 4 + 2]);
        acc[0][jj * 4 + 3] = fmaf(kq.x, vq.w, acc[0][jj * 4 + 3]);
        acc[1][jj * 4 + 0] = fmaf(kq.y, vq.x, acc[1][jj * 4 + 0]);
        acc[1][jj * 4 + 1] = fmaf(kq.y, vq.y, acc[1][jj * 4 + 1]);
        acc[1][jj * 4 + 2] = fmaf(kq.y, vq.z, acc[1][jj * 4 + 2]);
        acc[1][jj * 4 + 3] = fmaf(kq.y, vq.w, acc[1][jj * 4 + 3]);
        acc[2][jj * 4 + 0] = fmaf(kq.z, vq.x, acc[2][jj * 4 + 0]);
        acc[2][jj * 4 + 1] = fmaf(kq.z, vq.y, acc[2][jj * 4 + 1]);
        acc[2][jj * 4 + 2] = fmaf(kq.z, vq.z, acc[2][jj * 4 + 2]);
        acc[2][jj * 4 + 3] = fmaf(kq.z, vq.w, acc[2][jj * 4 + 3]);
        acc[3][jj * 4 + 0] = fmaf(kq.w, vq.x, acc[3][jj * 4 + 0]);
        acc[3][jj * 4 + 1] = fmaf(kq.w, vq.y, acc[3][jj * 4 + 1]);
        acc[3][jj * 4 + 2] = fmaf(kq.w, vq.z, acc[3][jj * 4 + 2]);
        acc[3][jj * 4 + 3] = fmaf(kq.w, vq.w, acc[3][jj * 4 + 3]);
      }
    }
  }
  float* dst = partial + ((long)chunk * 64 + bh) * 4096;
#pragma unroll
  for (int di = 0; di < 4; di++)
#pragma unroll
    for (int jj = 0; jj < 4; jj++) {
      float4 o = make_float4(acc[di][jj * 4], acc[di][jj * 4 + 1], acc[di][jj * 4 + 2],
                             acc[di][jj * 4 + 3]);
      *reinterpret_cast<float4*>(&dst[(d0 + di) * 64 + e0 + jj * 4]) = o;
    }
}

__global__ __launch_bounds__(256) void k_kv_reduce(const float* __restrict__ partial,
                                                   float* __restrict__ kv) {
  int i4 = (blockIdx.x * 256 + threadIdx.x) * 4;  // 0..262140, grid 256
  float4 s = make_float4(0.f, 0.f, 0.f, 0.f);
#pragma unroll
  for (int c = 0; c < 32; c++) {
    float4 p = *reinterpret_cast<const float4*>(&partial[(long)c * 262144 + i4]);
    s.x += p.x; s.y += p.y; s.z += p.z; s.w += p.w;
  }
  *reinterpret_cast<float4*>(&kv[i4]) = s;
}

// ---------------- fused weight: FW_b[n][h*64+d] = sum_e kv[b,h][d][e] * ow[n][h*64+e]
// written bf16 into the (dead) k-columns of qkv rows b*1024+n  -> GEMM2 B operand, ldb=3072.
__global__ __launch_bounds__(256) void k_fuse_w(const float* __restrict__ kv,
                                                const ushort_t* __restrict__ ow,
                                                ushort_t* __restrict__ qkv) {
  const int nt = blockIdx.x;  // 0..15
  const int h = blockIdx.y;   // 0..15
  const int b = blockIdx.z;   // 0..3
  const int t = threadIdx.x;
  const int nn = t >> 2;               // 0..63
  const int d0 = (t & 3) * 16;
  __shared__ float kvt[64][68];        // [e][d], padded
  __shared__ ushort_t ows[64][68];     // [n][e], padded
  const float* kvsrc = kv + (long)(b * 16 + h) * 4096;
  const int n0 = nt * 64;
#pragma unroll
  for (int rep = 0; rep < 16; rep++) {
    int lin = rep * 256 + t;
    int d = lin >> 6, e = lin & 63;
    kvt[e][d] = kvsrc[d * 64 + e];
  }
#pragma unroll
  for (int rep = 0; rep < 4; rep++) {
    int lin = rep * 256 + t;
    int r = lin >> 4, c4 = (lin & 15) * 4;
    *reinterpret_cast<ushort4*>(&ows[r][c4]) =
        *reinterpret_cast<const ushort4*>(&ow[(long)(n0 + r) * 1024 + h * 64 + c4]);
  }
  __syncthreads();
  float acc[16];
#pragma unroll
  for (int j = 0; j < 16; j++) acc[j] = 0.f;
  for (int e = 0; e < 64; e++) {
    float own = bf2f(ows[nn][e]);
#pragma unroll
    for (int jj = 0; jj < 4; jj++) {
      const float4 kq = *reinterpret_cast<const float4*>(&kvt[e][d0 + jj * 4]);
      acc[jj * 4 + 0] = fmaf(own, kq.x, acc[jj * 4 + 0]);
      acc[jj * 4 + 1] = fmaf(own, kq.y, acc[jj * 4 + 1]);
      acc[jj * 4 + 2] = fmaf(own, kq.z, acc[jj * 4 + 2]);
      acc[jj * 4 + 3] = fmaf(own, kq.w, acc[jj * 4 + 3]);
    }
  }
  ushort_t* dst = qkv + (long)(b * 1024 + n0 + nn) * 3072 + 1024 + h * 64 + d0;
#pragma unroll
  for (int jj = 0; jj < 4; jj++) {
    ushort4 o;
    o.x = f2bf(acc[jj * 4 + 0]); o.y = f2bf(acc[jj * 4 + 1]);
    o.z = f2bf(acc[jj * 4 + 2]); o.w = f2bf(acc[jj * 4 + 3]);
    *reinterpret_cast<ushort4*>(dst + jj * 4) = o;
  }
}

extern "C" void kernel_launch(void* const* d_in, const int* in_sizes, int n_in, void* d_out,
                              int out_size, void* d_ws, size_t ws_size, hipStream_t stream) {
  const float* x   = (const float*)d_in[0];
  const float* q_w = (const float*)d_in[1];
  const float* q_b = (const float*)d_in[2];
  const float* k_w = (const float*)d_in[3];
  const float* k_b = (const float*)d_in[4];
  const float* v_w = (const float*)d_in[5];
  const float* v_b = (const float*)d_in[6];
  const float* o_w = (const float*)d_in[7];
  const float* o_b = (const float*)d_in[8];
  float* out = (float*)d_out;

  const int D = 1024, M = 16384;
  char* ws = (char*)d_ws;
  // layout (bytes):
  ushort_t* xb    = (ushort_t*)(ws);              // 33,554,432  x as bf16
  ushort_t* wqkv  = (ushort_t*)(ws + 33554432);   //  6,291,456  [q_w;k_w;v_w] bf16
  ushort_t* owb   = (ushort_t*)(ws + 39845888);   //  2,097,152  o_w bf16 (follows wqkv contiguously)
  float*    biasq = (float*)(ws + 41943040);      //     12,288  [q_b;k_b;v_b]
  ushort_t* qkv   = (ushort_t*)(ws + 41955328);   // 100,663,296 [M][3072] bf16
  // xb region recycled after GEMM1:
  float* partial = (float*)(ws);                  // 33,554,432  [32][64][4096]
  // wqkv region recycled after GEMM1:
  float* kvbuf   = (float*)(ws + 33554432);       //  1,048,576  [64][64][64]

  // pack inputs to bf16
  k_f32_to_bf16<<<16384, 256, 0, stream>>>(x, xb, M * D);
  k_pack_w4<<<4096, 256, 0, stream>>>(q_w, k_w, v_w, o_w, wqkv);
  hipMemcpyAsync(biasq, q_b, D * sizeof(float), hipMemcpyDeviceToDevice, stream);
  hipMemcpyAsync(biasq + D, k_b, D * sizeof(float), hipMemcpyDeviceToDevice, stream);
  hipMemcpyAsync(biasq + 2 * D, v_b, D * sizeof(float), hipMemcpyDeviceToDevice, stream);

  // QKV projection: [16384 x 1024] x [3072 x 1024]^T, bias + relu on q,k cols (<2048)
  k_gemm_bt<false><<<dim3(24, 128), 256, 0, stream>>>(xb, 1024, wqkv, 1024, biasq, 2048,
                                                      qkv, 3072, 1024);
  // KV state (two-stage deterministic reduction over S)
  k_kv_partial<<<dim3(64, 32), 64, 0, stream>>>(qkv, partial);
  k_kv_reduce<<<256, 256, 0, stream>>>(partial, kvbuf);
  // fold KV into o_w: per-batch fused weight, stored in dead k-columns of qkv rows 0..4095
  k_fuse_w<<<dim3(16, 16, 4), 256, 0, stream>>>(kvbuf, owb, qkv);
  // out_b = relu(q)_b @ FW_b^T + o_b   (4 per-batch GEMMs; A = q cols, B = FW in k cols)
  for (int b = 0; b < 4; b++) {
    k_gemm_bt<true><<<dim3(8, 32), 256, 0, stream>>>(
        qkv + (long)b * 4096 * 3072, 3072, qkv + (long)b * 1024 * 3072 + 1024, 3072,
        o_b, 0, out + (long)b * 4096 * 1024, 1024, 1024);
  }
}

// Round 3
// 253.019 us; speedup vs baseline: 1.3919x; 1.3689x over previous
//
#include <hip/hip_runtime.h>

typedef unsigned short ushort_t;
typedef __attribute__((ext_vector_type(8))) __bf16 bf16x8;
typedef __attribute__((ext_vector_type(4))) float f32x4;

// async global->LDS, 16B per lane. LDS dest is wave-uniform base + lane*16 (m97/m104).
#define GLOAD_LDS16(gp, lp)                                                              \
  __builtin_amdgcn_global_load_lds(                                                     \
      (const __attribute__((address_space(1))) unsigned int*)(gp),                      \
      (__attribute__((address_space(3))) unsigned int*)(lp), 16, 0, 0)

#define MEMFENCE() asm volatile("" ::: "memory")
#define SBARRIER()                          \
  do {                                      \
    MEMFENCE();                             \
    __builtin_amdgcn_s_barrier();           \
    MEMFENCE();                             \
  } while (0)
// rule #18: inline-asm lgkmcnt needs a following sched_barrier(0)
#define WAIT_LGKM0()                                     \
  do {                                                   \
    asm volatile("s_waitcnt lgkmcnt(0)" ::: "memory");   \
    __builtin_amdgcn_sched_barrier(0);                   \
  } while (0)
#define WAIT_VM2() asm volatile("s_waitcnt vmcnt(2)" ::: "memory")

__device__ __forceinline__ ushort_t f2bf(float f) {
  unsigned u = __builtin_bit_cast(unsigned, f);
  u += 0x7fffu + ((u >> 16) & 1u);  // RNE
  return (ushort_t)(u >> 16);
}
__device__ __forceinline__ float bf2f(ushort_t h) {
  return __builtin_bit_cast(float, (unsigned)h << 16);
}

// ---------------- pack: f32 -> bf16 ----------------
__global__ __launch_bounds__(256) void k_f32_to_bf16(const float* __restrict__ src,
                                                     ushort_t* __restrict__ dst, int n) {
  int i = (blockIdx.x * 256 + threadIdx.x) * 4;
  if (i >= n) return;
  float4 v = *reinterpret_cast<const float4*>(src + i);
  ushort4 o;
  o.x = f2bf(v.x); o.y = f2bf(v.y); o.z = f2bf(v.z); o.w = f2bf(v.w);
  *reinterpret_cast<ushort4*>(dst + i) = o;
}

__global__ __launch_bounds__(256) void k_pack_w4(const float* __restrict__ w0,
                                                 const float* __restrict__ w1,
                                                 const float* __restrict__ w2,
                                                 const float* __restrict__ w3,
                                                 ushort_t* __restrict__ dst) {
  const int blk = blockIdx.x;  // 0..4095
  const int wsel = blk >> 10;
  const float* src = wsel == 0 ? w0 : wsel == 1 ? w1 : wsel == 2 ? w2 : w3;
  const int off = (blk & 1023) * 1024 + threadIdx.x * 4;
  float4 v = *reinterpret_cast<const float4*>(src + off);
  ushort4 o;
  o.x = f2bf(v.x); o.y = f2bf(v.y); o.z = f2bf(v.z); o.w = f2bf(v.w);
  *reinterpret_cast<ushort4*>(dst + wsel * 1048576 + off) = o;
}

// ---------------- 256x256 8-phase GEMM (T1+T2+T3+T4+T5), BK=64, 8 waves (2Mx4N) ------
// C[m][n] = sum_k A[m][k]*Bw[n][k] + bias[n], relu if n < relu_lim.
// LDS: buf(2) x op(A,B) x half(2) slots of [128][64] bf16 (16 KiB each) = 128 KiB.
// st_16x32 swizzle: linear LDS dest; inverse-swizzled GLOBAL source + swizzled ds_read.

__device__ __forceinline__ void stage_half(const ushort_t* __restrict__ g, int ld, int kt,
                                           ushort_t* slot, int w, int lane) {
#pragma unroll
  for (int l = 0; l < 2; l++) {
    int elemP = l * 4096 + w * 512 + lane * 8;       // dest elem pos (linear)
    int row = elemP >> 6;
    int kk = (elemP & 63) ^ ((lane & 32) >> 1);      // inverse st_16x32 on source
    GLOAD_LDS16(g + (long)row * ld + kt + kk, slot + l * 4096 + w * 512);
  }
}

__device__ __forceinline__ bf16x8 read_frag(const ushort_t* slot, int row, int kb) {
  int byte = row * 128 + (kb ^ (((row >> 2) & 1) << 5));  // st_16x32
  return *reinterpret_cast<const bf16x8*>(reinterpret_cast<const char*>(slot) + byte);
}

template <bool OUT_F32>
__global__ __launch_bounds__(512, 2) void k_gemm256(
    const ushort_t* __restrict__ A, int lda, long strideA,
    const ushort_t* __restrict__ Bw, int ldb, long strideB,
    const float* __restrict__ bias, int relu_lim,
    void* __restrict__ Cout, int ldc, long strideC, int K) {
  __shared__ ushort_t lds[65536];  // 128 KiB
  const int t = threadIdx.x;
  const int lane = t & 63;
  const int w = t >> 6;
  const int wm = w >> 2, wn = w & 3;
  const int z = blockIdx.z;

  // XCD-aware swizzle (nwg % 8 == 0 in all our launches -> simple form bijective)
  const int nx = gridDim.x;
  const int nwg = nx * gridDim.y;
  const int lin = blockIdx.x + blockIdx.y * nx;
  const int q8 = nwg >> 3;
  const int s = (lin & 7) * q8 + (lin >> 3);
  const long rowBase = (long)(s / nx) * 256;
  const long colBase = (long)(s % nx) * 256;

  const ushort_t* Ap = A + z * strideA + rowBase * lda;
  const ushort_t* Bp = Bw + z * strideB + colBase * ldb;

#define SLOT(buf, isB, half) (lds + (buf) * 32768 + (isB) * 16384 + (half) * 8192)
#define STAGE(gb, ld, kt, buf, isB, half) stage_half((gb), (ld), (kt), SLOT(buf, isB, half), w, lane)

  f32x4 acc[8][4];
#pragma unroll
  for (int mi = 0; mi < 8; mi++)
#pragma unroll
    for (int ni = 0; ni < 4; ni++) acc[mi][ni] = (f32x4){0.f, 0.f, 0.f, 0.f};
  bf16x8 Ar[4][2], Br[4][2];
  const int fr = lane & 15;
  const int kb = (lane >> 4) * 16;  // byte offset within 64-elem k (per ks add ks*64)

#define LOADA(buf, miB)                                                             \
  do {                                                                              \
    const ushort_t* sl = SLOT(buf, 0, wm);                                          \
    _Pragma("unroll") for (int mi = 0; mi < 4; mi++)                                \
        _Pragma("unroll") for (int ks = 0; ks < 2; ks++)                            \
            Ar[mi][ks] = read_frag(sl, (miB + mi) * 16 + fr, ks * 64 + kb);         \
  } while (0)
#define LOADB(buf, ns)                                                              \
  do {                                                                              \
    const ushort_t* sl = SLOT(buf, 1, wn >> 1);                                     \
    _Pragma("unroll") for (int nj = 0; nj < 2; nj++)                                \
        _Pragma("unroll") for (int ks = 0; ks < 2; ks++)                            \
            Br[(ns) * 2 + nj][ks] =                                                 \
                read_frag(sl, (wn & 1) * 64 + ((ns) * 2 + nj) * 16 + fr, ks * 64 + kb); \
  } while (0)
#define MFMA16(miB, ns)                                                             \
  do {                                                                              \
    _Pragma("unroll") for (int ks = 0; ks < 2; ks++)                                \
        _Pragma("unroll") for (int mi = 0; mi < 4; mi++)                            \
            _Pragma("unroll") for (int nj = 0; nj < 2; nj++)                        \
                acc[(miB) + mi][(ns) * 2 + nj] = __builtin_amdgcn_mfma_f32_16x16x32_bf16( \
                    Ar[mi][ks], Br[(ns) * 2 + nj][ks], acc[(miB) + mi][(ns) * 2 + nj], 0, 0, 0); \
  } while (0)

  const ushort_t* Ap1 = Ap + 128 * (long)lda;
  const ushort_t* Bp1 = Bp + 128 * (long)ldb;

  // Prologue: tile0 (A0,B0,A1,B1 -> buf0) + tile1.A0 -> buf1; drain tile0.
  STAGE(Ap, lda, 0, 0, 0, 0);
  STAGE(Bp, ldb, 0, 0, 1, 0);
  STAGE(Ap1, lda, 0, 0, 0, 1);
  STAGE(Bp1, ldb, 0, 0, 1, 1);
  STAGE(Ap, lda, 64, 1, 0, 0);
  WAIT_VM2();
  SBARRIER();

  const int NT2 = K >> 7;  // K/128, 2 K-tiles per iteration
  for (int it = 0; it < NT2; it++) {
    const int kt = it << 7;
    const int ktb = kt + 64;
    const int ktn = (kt + 128 < K) ? kt + 128 : K - 64;   // clamped re-stage is benign
    const int ktn2 = (kt + 192 < K) ? kt + 192 : K - 64;

    // P1: reads buf0 A[m0-3],B[n0-1]; stage (t+1).B0 -> buf1
    LOADA(0, 0); LOADB(0, 0);
    STAGE(Bp, ldb, ktb, 1, 1, 0);
    SBARRIER(); WAIT_LGKM0();
    __builtin_amdgcn_s_setprio(1); MFMA16(0, 0); __builtin_amdgcn_s_setprio(0);
    SBARRIER();
    // P2: reads buf0 B[n2-3]; stage (t+1).A1 -> buf1
    LOADB(0, 1);
    STAGE(Ap1, lda, ktb, 1, 0, 1);
    SBARRIER(); WAIT_LGKM0();
    __builtin_amdgcn_s_setprio(1); MFMA16(0, 1); __builtin_amdgcn_s_setprio(0);
    SBARRIER();
    // P3: reads buf0 A[m4-7]; stage (t+1).B1 -> buf1
    LOADA(0, 4);
    STAGE(Bp1, ldb, ktb, 1, 1, 1);
    SBARRIER(); WAIT_LGKM0();
    __builtin_amdgcn_s_setprio(1); MFMA16(4, 0); __builtin_amdgcn_s_setprio(0);
    SBARRIER();
    // P4: no reads; stage (t+2).A0 -> buf0; drain all but newest stage
    STAGE(Ap, lda, ktn, 0, 0, 0);
    SBARRIER(); WAIT_LGKM0();
    __builtin_amdgcn_s_setprio(1); MFMA16(4, 1); __builtin_amdgcn_s_setprio(0);
    WAIT_VM2();
    SBARRIER();
    // P5: reads buf1 A[m0-3],B[n0-1]; stage (t+2).B0 -> buf0
    LOADA(1, 0); LOADB(1, 0);
    STAGE(Bp, ldb, ktn, 0, 1, 0);
    SBARRIER(); WAIT_LGKM0();
    __builtin_amdgcn_s_setprio(1); MFMA16(0, 0); __builtin_amdgcn_s_setprio(0);
    SBARRIER();
    // P6: reads buf1 B[n2-3]; stage (t+2).A1 -> buf0
    LOADB(1, 1);
    STAGE(Ap1, lda, ktn, 0, 0, 1);
    SBARRIER(); WAIT_LGKM0();
    __builtin_amdgcn_s_setprio(1); MFMA16(0, 1); __builtin_amdgcn_s_setprio(0);
    SBARRIER();
    // P7: reads buf1 A[m4-7]; stage (t+2).B1 -> buf0
    LOADA(1, 4);
    STAGE(Bp1, ldb, ktn, 0, 1, 1);
    SBARRIER(); WAIT_LGKM0();
    __builtin_amdgcn_s_setprio(1); MFMA16(4, 0); __builtin_amdgcn_s_setprio(0);
    SBARRIER();
    // P8: stage (t+3).A0 -> buf1; drain all but newest stage
    STAGE(Ap, lda, ktn2, 1, 0, 0);
    SBARRIER(); WAIT_LGKM0();
    __builtin_amdgcn_s_setprio(1); MFMA16(4, 1); __builtin_amdgcn_s_setprio(0);
    WAIT_VM2();
    SBARRIER();
  }

  // Epilogue: C/D layout col=lane&15, row=(lane>>4)*4+r (m89-verified)
  const int rowQ = (lane >> 4) * 4;
#pragma unroll
  for (int ni = 0; ni < 4; ni++) {
    const int col = (int)colBase + wn * 64 + ni * 16 + fr;
    const float bv = bias[col];
    const bool doRelu = col < relu_lim;
#pragma unroll
    for (int mi = 0; mi < 8; mi++) {
      const long row = rowBase + wm * 128 + mi * 16 + rowQ;
#pragma unroll
      for (int r = 0; r < 4; r++) {
        float v = acc[mi][ni][r] + bv;
        if (doRelu) v = fmaxf(v, 0.f);
        if (OUT_F32)
          ((float*)Cout)[z * strideC + (row + r) * (long)ldc + col] = v;
        else
          ((ushort_t*)Cout)[z * strideC + (row + r) * (long)ldc + col] = f2bf(v);
      }
    }
  }
#undef SLOT
#undef STAGE
#undef LOADA
#undef LOADB
#undef MFMA16
}

// ---------------- KV state partials ----------------
__global__ __launch_bounds__(64) void k_kv_partial(const ushort_t* __restrict__ qkv,
                                                   float* __restrict__ partial) {
  const int bh = blockIdx.x;
  const int chunk = blockIdx.y;
  const int b = bh >> 4, h = bh & 15;
  const int t = threadIdx.x;
  const int d0 = (t >> 2) * 4;
  const int e0 = (t & 3) * 16;
  __shared__ float kk[16][64];
  __shared__ float vv[16][64];
  float acc[4][16];
#pragma unroll
  for (int di = 0; di < 4; di++)
#pragma unroll
    for (int j = 0; j < 16; j++) acc[di][j] = 0.f;

  const long rowbase = (long)b * 4096 + (long)chunk * 128;
  for (int it = 0; it < 8; it++) {
    __syncthreads();
#pragma unroll
    for (int rep = 0; rep < 4; rep++) {
      int idx = rep * 64 + t;
      int row = idx >> 4, c4 = (idx & 15) * 4;
      long m = rowbase + it * 16 + row;
      ushort4 kr = *reinterpret_cast<const ushort4*>(&qkv[m * 3072 + 1024 + h * 64 + c4]);
      ushort4 vr = *reinterpret_cast<const ushort4*>(&qkv[m * 3072 + 2048 + h * 64 + c4]);
      float4 kf = make_float4(bf2f(kr.x), bf2f(kr.y), bf2f(kr.z), bf2f(kr.w));
      float4 vf = make_float4(bf2f(vr.x), bf2f(vr.y), bf2f(vr.z), bf2f(vr.w));
      *reinterpret_cast<float4*>(&kk[row][c4]) = kf;
      *reinterpret_cast<float4*>(&vv[row][c4]) = vf;
    }
    __syncthreads();
#pragma unroll
    for (int ss = 0; ss < 16; ss++) {
      const float4 kq = *reinterpret_cast<const float4*>(&kk[ss][d0]);
#pragma unroll
      for (int jj = 0; jj < 4; jj++) {
        const float4 vq = *reinterpret_cast<const float4*>(&vv[ss][e0 + jj * 4]);
        acc[0][jj * 4 + 0] = fmaf(kq.x, vq.x, acc[0][jj * 4 + 0]);
        acc[0][jj * 4 + 1] = fmaf(kq.x, vq.y, acc[0][jj * 4 + 1]);
        acc[0][jj * 4 + 2] = fmaf(kq.x, vq.z, acc[0][jj * 4 + 2]);
        acc[0][jj * 4 + 3] = fmaf(kq.x, vq.w, acc[0][jj * 4 + 3]);
        acc[1][jj * 4 + 0] = fmaf(kq.y, vq.x, acc[1][jj * 4 + 0]);
        acc[1][jj * 4 + 1] = fmaf(kq.y, vq.y, acc[1][jj * 4 + 1]);
        acc[1][jj * 4 + 2] = fmaf(kq.y, vq.z, acc[1][jj * 4 + 2]);
        acc[1][jj * 4 + 3] = fmaf(kq.y, vq.w, acc[1][jj * 4 + 3]);
        acc[2][jj * 4 + 0] = fmaf(kq.z, vq.x, acc[2][jj * 4 + 0]);
        acc[2][jj * 4 + 1] = fmaf(kq.z, vq.y, acc[2][jj * 4 + 1]);
        acc[2][jj * 4 + 2] = fmaf(kq.z, vq.z, acc[2][jj * 4 + 2]);
        acc[2][jj * 4 + 3] = fmaf(kq.z, vq.w, acc[2][jj * 4 + 3]);
        acc[3][jj * 4 + 0] = fmaf(kq.w, vq.x, acc[3][jj * 4 + 0]);
        acc[3][jj * 4 + 1] = fmaf(kq.w, vq.y, acc[3][jj * 4 + 1]);
        acc[3][jj * 4 + 2] = fmaf(kq.w, vq.z, acc[3][jj * 4 + 2]);
        acc[3][jj * 4 + 3] = fmaf(kq.w, vq.w, acc[3][jj * 4 + 3]);
      }
    }
  }
  float* dst = partial + ((long)chunk * 64 + bh) * 4096;
#pragma unroll
  for (int di = 0; di < 4; di++)
#pragma unroll
    for (int jj = 0; jj < 4; jj++) {
      float4 o = make_float4(acc[di][jj * 4], acc[di][jj * 4 + 1], acc[di][jj * 4 + 2],
                             acc[di][jj * 4 + 3]);
      *reinterpret_cast<float4*>(&dst[(d0 + di) * 64 + e0 + jj * 4]) = o;
    }
}

__global__ __launch_bounds__(256) void k_kv_reduce(const float* __restrict__ partial,
                                                   float* __restrict__ kv) {
  int i4 = (blockIdx.x * 256 + threadIdx.x) * 4;
  float4 s = make_float4(0.f, 0.f, 0.f, 0.f);
#pragma unroll
  for (int c = 0; c < 32; c++) {
    float4 p = *reinterpret_cast<const float4*>(&partial[(long)c * 262144 + i4]);
    s.x += p.x; s.y += p.y; s.z += p.z; s.w += p.w;
  }
  *reinterpret_cast<float4*>(&kv[i4]) = s;
}

// ---------------- fused weight: FW_b[n][h*64+d] = sum_e kv[b,h][d][e] * ow[n][h*64+e]
__global__ __launch_bounds__(256) void k_fuse_w(const float* __restrict__ kv,
                                                const ushort_t* __restrict__ ow,
                                                ushort_t* __restrict__ qkv) {
  const int nt = blockIdx.x;
  const int h = blockIdx.y;
  const int b = blockIdx.z;
  const int t = threadIdx.x;
  const int nn = t >> 2;
  const int d0 = (t & 3) * 16;
  __shared__ float kvt[64][68];
  __shared__ ushort_t ows[64][68];
  const float* kvsrc = kv + (long)(b * 16 + h) * 4096;
  const int n0 = nt * 64;
#pragma unroll
  for (int rep = 0; rep < 16; rep++) {
    int lin = rep * 256 + t;
    int d = lin >> 6, e = lin & 63;
    kvt[e][d] = kvsrc[d * 64 + e];
  }
#pragma unroll
  for (int rep = 0; rep < 4; rep++) {
    int lin = rep * 256 + t;
    int r = lin >> 4, c4 = (lin & 15) * 4;
    *reinterpret_cast<ushort4*>(&ows[r][c4]) =
        *reinterpret_cast<const ushort4*>(&ow[(long)(n0 + r) * 1024 + h * 64 + c4]);
  }
  __syncthreads();
  float acc[16];
#pragma unroll
  for (int j = 0; j < 16; j++) acc[j] = 0.f;
  for (int e = 0; e < 64; e++) {
    float own = bf2f(ows[nn][e]);
#pragma unroll
    for (int jj = 0; jj < 4; jj++) {
      const float4 kq = *reinterpret_cast<const float4*>(&kvt[e][d0 + jj * 4]);
      acc[jj * 4 + 0] = fmaf(own, kq.x, acc[jj * 4 + 0]);
      acc[jj * 4 + 1] = fmaf(own, kq.y, acc[jj * 4 + 1]);
      acc[jj * 4 + 2] = fmaf(own, kq.z, acc[jj * 4 + 2]);
      acc[jj * 4 + 3] = fmaf(own, kq.w, acc[jj * 4 + 3]);
    }
  }
  ushort_t* dst = qkv + (long)(b * 1024 + n0 + nn) * 3072 + 1024 + h * 64 + d0;
#pragma unroll
  for (int jj = 0; jj < 4; jj++) {
    ushort4 o;
    o.x = f2bf(acc[jj * 4 + 0]); o.y = f2bf(acc[jj * 4 + 1]);
    o.z = f2bf(acc[jj * 4 + 2]); o.w = f2bf(acc[jj * 4 + 3]);
    *reinterpret_cast<ushort4*>(dst + jj * 4) = o;
  }
}

extern "C" void kernel_launch(void* const* d_in, const int* in_sizes, int n_in, void* d_out,
                              int out_size, void* d_ws, size_t ws_size, hipStream_t stream) {
  const float* x   = (const float*)d_in[0];
  const float* q_w = (const float*)d_in[1];
  const float* q_b = (const float*)d_in[2];
  const float* k_w = (const float*)d_in[3];
  const float* k_b = (const float*)d_in[4];
  const float* v_w = (const float*)d_in[5];
  const float* v_b = (const float*)d_in[6];
  const float* o_w = (const float*)d_in[7];
  const float* o_b = (const float*)d_in[8];
  float* out = (float*)d_out;

  const int D = 1024, M = 16384;
  char* ws = (char*)d_ws;
  ushort_t* xb    = (ushort_t*)(ws);              // 33,554,432  x as bf16
  ushort_t* wqkv  = (ushort_t*)(ws + 33554432);   //  6,291,456  [q_w;k_w;v_w] bf16
  ushort_t* owb   = (ushort_t*)(ws + 39845888);   //  2,097,152  o_w bf16
  float*    biasq = (float*)(ws + 41943040);      //     12,288  [q_b;k_b;v_b]
  ushort_t* qkv   = (ushort_t*)(ws + 41955328);   // 100,663,296 [M][3072] bf16
  float* partial = (float*)(ws);                  // 33,554,432  [32][64][4096] (recycles xb)
  float* kvbuf   = (float*)(ws + 33554432);       //  1,048,576  (recycles wqkv)

  k_f32_to_bf16<<<16384, 256, 0, stream>>>(x, xb, M * D);
  k_pack_w4<<<4096, 256, 0, stream>>>(q_w, k_w, v_w, o_w, wqkv);
  hipMemcpyAsync(biasq, q_b, D * sizeof(float), hipMemcpyDeviceToDevice, stream);
  hipMemcpyAsync(biasq + D, k_b, D * sizeof(float), hipMemcpyDeviceToDevice, stream);
  hipMemcpyAsync(biasq + 2 * D, v_b, D * sizeof(float), hipMemcpyDeviceToDevice, stream);

  // QKV projection: [16384 x 1024] x [3072 x 1024]^T (+bias, relu on cols<2048)
  k_gemm256<false><<<dim3(12, 64, 1), 512, 0, stream>>>(xb, 1024, 0, wqkv, 1024, 0,
                                                        biasq, 2048, qkv, 3072, 0, 1024);
  // KV state
  k_kv_partial<<<dim3(64, 32), 64, 0, stream>>>(qkv, partial);
  k_kv_reduce<<<256, 256, 0, stream>>>(partial, kvbuf);
  // fold KV into o_w (per-batch fused weight in dead k-columns of qkv rows 0..4095)
  k_fuse_w<<<dim3(16, 16, 4), 256, 0, stream>>>(kvbuf, owb, qkv);
  // out_b = relu(q)_b @ FW_b^T + o_b  — single batched launch (grid.z = 4)
  k_gemm256<true><<<dim3(4, 16, 4), 512, 0, stream>>>(
      qkv, 3072, (long)4096 * 3072, qkv + 1024, 3072, (long)1024 * 3072,
      o_b, 0, out, 1024, (long)4096 * 1024, 1024);
}

// Round 4
// 243.538 us; speedup vs baseline: 1.4461x; 1.0389x over previous
//
#include <hip/hip_runtime.h>

typedef unsigned short ushort_t;
typedef __attribute__((ext_vector_type(8))) __bf16 bf16x8;
typedef __attribute__((ext_vector_type(4))) float f32x4;

// async global->LDS, 16B per lane. LDS dest is wave-uniform base + lane*16 (m97/m104).
#define GLOAD_LDS16(gp, lp)                                                              \
  __builtin_amdgcn_global_load_lds(                                                     \
      (const __attribute__((address_space(1))) unsigned int*)(gp),                      \
      (__attribute__((address_space(3))) unsigned int*)(lp), 16, 0, 0)

#define MEMFENCE() asm volatile("" ::: "memory")
#define SBARRIER()                          \
  do {                                      \
    MEMFENCE();                             \
    __builtin_amdgcn_s_barrier();           \
    MEMFENCE();                             \
  } while (0)
// rule #18: inline-asm lgkmcnt needs a following sched_barrier(0)
#define WAIT_LGKM0()                                     \
  do {                                                   \
    asm volatile("s_waitcnt lgkmcnt(0)" ::: "memory");   \
    __builtin_amdgcn_sched_barrier(0);                   \
  } while (0)
#define WAIT_VM2() asm volatile("s_waitcnt vmcnt(2)" ::: "memory")

__device__ __forceinline__ ushort_t f2bf(float f) {
  unsigned u = __builtin_bit_cast(unsigned, f);
  u += 0x7fffu + ((u >> 16) & 1u);  // RNE
  return (ushort_t)(u >> 16);
}
__device__ __forceinline__ float bf2f(ushort_t h) {
  return __builtin_bit_cast(float, (unsigned)h << 16);
}

// ---------------- pack: f32 -> bf16 ----------------
__global__ __launch_bounds__(256) void k_f32_to_bf16(const float* __restrict__ src,
                                                     ushort_t* __restrict__ dst, int n) {
  int i = (blockIdx.x * 256 + threadIdx.x) * 4;
  if (i >= n) return;
  float4 v = *reinterpret_cast<const float4*>(src + i);
  ushort4 o;
  o.x = f2bf(v.x); o.y = f2bf(v.y); o.z = f2bf(v.z); o.w = f2bf(v.w);
  *reinterpret_cast<ushort4*>(dst + i) = o;
}

__global__ __launch_bounds__(256) void k_pack_w4(const float* __restrict__ w0,
                                                 const float* __restrict__ w1,
                                                 const float* __restrict__ w2,
                                                 const float* __restrict__ w3,
                                                 ushort_t* __restrict__ dst) {
  const int blk = blockIdx.x;  // 0..4095
  const int wsel = blk >> 10;
  const float* src = wsel == 0 ? w0 : wsel == 1 ? w1 : wsel == 2 ? w2 : w3;
  const int off = (blk & 1023) * 1024 + threadIdx.x * 4;
  float4 v = *reinterpret_cast<const float4*>(src + off);
  ushort4 o;
  o.x = f2bf(v.x); o.y = f2bf(v.y); o.z = f2bf(v.z); o.w = f2bf(v.w);
  *reinterpret_cast<ushort4*>(dst + wsel * 1048576 + off) = o;
}

// ---------------- 256x256 8-phase GEMM (T1+T2+T3+T4+T5), BK=64, 8 waves (2Mx4N) ------
// C[m][n] = sum_k A[m][k]*Bw[n][k] + bias[n], relu if n < relu_lim.
// LDS: buf(2) x op(A,B) x half(2) slots of [128][64] bf16 (16 KiB each) = 128 KiB.
// T2 swizzle (G4 recipe, full row&7): read byte = row*128 + (kbyte ^ ((row&7)<<4));
// LDS dest linear, inverse swizzle applied to the GLOBAL source k-unit (rule #21).

__device__ __forceinline__ void stage_half(const ushort_t* __restrict__ g, int ld, int kt,
                                           ushort_t* slot, int w, int lane) {
  // dest 16B-unit for lane: row&7 == lane>>3, slotpos == lane&7
  // inverse swizzle: source k-unit = (lane&7) ^ (lane>>3)
  const int swz = ((lane & 7) ^ (lane >> 3)) * 8;  // elems
#pragma unroll
  for (int l = 0; l < 2; l++) {
    int row = l * 64 + w * 8 + (lane >> 3);
    GLOAD_LDS16(g + (long)row * ld + kt + swz, slot + l * 4096 + w * 512);
  }
}

__device__ __forceinline__ bf16x8 read_frag(const ushort_t* slot, int row, int kbyte) {
  int byte = row * 128 + (kbyte ^ ((row & 7) << 4));  // full 3-bit XOR: 8-slot spread
  return *reinterpret_cast<const bf16x8*>(reinterpret_cast<const char*>(slot) + byte);
}

template <bool OUT_F32>
__global__ __launch_bounds__(512, 2) void k_gemm256(
    const ushort_t* __restrict__ A, int lda, long strideA,
    const ushort_t* __restrict__ Bw, int ldb, long strideB,
    const float* __restrict__ bias, int relu_lim,
    void* __restrict__ Cout, int ldc, long strideC, int K) {
  __shared__ ushort_t lds[65536];  // 128 KiB
  const int t = threadIdx.x;
  const int lane = t & 63;
  const int w = t >> 6;
  const int wm = w >> 2, wn = w & 3;
  const int z = blockIdx.z;

  // XCD-aware swizzle (nwg % 8 == 0 in all our launches -> simple form bijective)
  const int nx = gridDim.x;
  const int nwg = nx * gridDim.y;
  const int lin = blockIdx.x + blockIdx.y * nx;
  const int q8 = nwg >> 3;
  const int s = (lin & 7) * q8 + (lin >> 3);
  const long rowBase = (long)(s / nx) * 256;
  const long colBase = (long)(s % nx) * 256;

  const ushort_t* Ap = A + z * strideA + rowBase * lda;
  const ushort_t* Bp = Bw + z * strideB + colBase * ldb;

#define SLOT(buf, isB, half) (lds + (buf) * 32768 + (isB) * 16384 + (half) * 8192)
#define STAGE(gb, ld, kt, buf, isB, half) stage_half((gb), (ld), (kt), SLOT(buf, isB, half), w, lane)

  f32x4 acc[8][4];
#pragma unroll
  for (int mi = 0; mi < 8; mi++)
#pragma unroll
    for (int ni = 0; ni < 4; ni++) acc[mi][ni] = (f32x4){0.f, 0.f, 0.f, 0.f};
  bf16x8 Ar[4][2], Br[4][2];
  const int fr = lane & 15;
  const int kb = (lane >> 4) * 16;  // byte offset within 64-elem k (per ks add ks*64)

#define LOADA(buf, miB)                                                             \
  do {                                                                              \
    const ushort_t* sl = SLOT(buf, 0, wm);                                          \
    _Pragma("unroll") for (int mi = 0; mi < 4; mi++)                                \
        _Pragma("unroll") for (int ks = 0; ks < 2; ks++)                            \
            Ar[mi][ks] = read_frag(sl, (miB + mi) * 16 + fr, ks * 64 + kb);         \
  } while (0)
#define LOADB(buf, ns)                                                              \
  do {                                                                              \
    const ushort_t* sl = SLOT(buf, 1, wn >> 1);                                     \
    _Pragma("unroll") for (int nj = 0; nj < 2; nj++)                                \
        _Pragma("unroll") for (int ks = 0; ks < 2; ks++)                            \
            Br[(ns) * 2 + nj][ks] =                                                 \
                read_frag(sl, (wn & 1) * 64 + ((ns) * 2 + nj) * 16 + fr, ks * 64 + kb); \
  } while (0)
#define MFMA16(miB, ns)                                                             \
  do {                                                                              \
    _Pragma("unroll") for (int ks = 0; ks < 2; ks++)                                \
        _Pragma("unroll") for (int mi = 0; mi < 4; mi++)                            \
            _Pragma("unroll") for (int nj = 0; nj < 2; nj++)                        \
                acc[(miB) + mi][(ns) * 2 + nj] = __builtin_amdgcn_mfma_f32_16x16x32_bf16( \
                    Ar[mi][ks], Br[(ns) * 2 + nj][ks], acc[(miB) + mi][(ns) * 2 + nj], 0, 0, 0); \
  } while (0)

  const ushort_t* Ap1 = Ap + 128 * (long)lda;
  const ushort_t* Bp1 = Bp + 128 * (long)ldb;

  // Prologue: tile0 (A0,B0,A1,B1 -> buf0) + tile1.A0 -> buf1; drain tile0.
  STAGE(Ap, lda, 0, 0, 0, 0);
  STAGE(Bp, ldb, 0, 0, 1, 0);
  STAGE(Ap1, lda, 0, 0, 0, 1);
  STAGE(Bp1, ldb, 0, 0, 1, 1);
  STAGE(Ap, lda, 64, 1, 0, 0);
  WAIT_VM2();
  SBARRIER();

  const int NT2 = K >> 7;  // K/128, 2 K-tiles per iteration
  for (int it = 0; it < NT2; it++) {
    const int kt = it << 7;
    const int ktb = kt + 64;
    const int ktn = (kt + 128 < K) ? kt + 128 : K - 64;   // clamped re-stage is benign
    const int ktn2 = (kt + 192 < K) ? kt + 192 : K - 64;

    // P1: reads buf0 A[m0-3],B[n0-1]; stage (t+1).B0 -> buf1
    LOADA(0, 0); LOADB(0, 0);
    STAGE(Bp, ldb, ktb, 1, 1, 0);
    SBARRIER(); WAIT_LGKM0();
    __builtin_amdgcn_s_setprio(1); MFMA16(0, 0); __builtin_amdgcn_s_setprio(0);
    SBARRIER();
    // P2: reads buf0 B[n2-3]; stage (t+1).A1 -> buf1
    LOADB(0, 1);
    STAGE(Ap1, lda, ktb, 1, 0, 1);
    SBARRIER(); WAIT_LGKM0();
    __builtin_amdgcn_s_setprio(1); MFMA16(0, 1); __builtin_amdgcn_s_setprio(0);
    SBARRIER();
    // P3: reads buf0 A[m4-7]; stage (t+1).B1 -> buf1
    LOADA(0, 4);
    STAGE(Bp1, ldb, ktb, 1, 1, 1);
    SBARRIER(); WAIT_LGKM0();
    __builtin_amdgcn_s_setprio(1); MFMA16(4, 0); __builtin_amdgcn_s_setprio(0);
    SBARRIER();
    // P4: no reads; stage (t+2).A0 -> buf0; drain all but newest stage
    STAGE(Ap, lda, ktn, 0, 0, 0);
    SBARRIER(); WAIT_LGKM0();
    __builtin_amdgcn_s_setprio(1); MFMA16(4, 1); __builtin_amdgcn_s_setprio(0);
    WAIT_VM2();
    SBARRIER();
    // P5: reads buf1 A[m0-3],B[n0-1]; stage (t+2).B0 -> buf0
    LOADA(1, 0); LOADB(1, 0);
    STAGE(Bp, ldb, ktn, 0, 1, 0);
    SBARRIER(); WAIT_LGKM0();
    __builtin_amdgcn_s_setprio(1); MFMA16(0, 0); __builtin_amdgcn_s_setprio(0);
    SBARRIER();
    // P6: reads buf1 B[n2-3]; stage (t+2).A1 -> buf0
    LOADB(1, 1);
    STAGE(Ap1, lda, ktn, 0, 0, 1);
    SBARRIER(); WAIT_LGKM0();
    __builtin_amdgcn_s_setprio(1); MFMA16(0, 1); __builtin_amdgcn_s_setprio(0);
    SBARRIER();
    // P7: reads buf1 A[m4-7]; stage (t+2).B1 -> buf0
    LOADA(1, 4);
    STAGE(Bp1, ldb, ktn, 0, 1, 1);
    SBARRIER(); WAIT_LGKM0();
    __builtin_amdgcn_s_setprio(1); MFMA16(4, 0); __builtin_amdgcn_s_setprio(0);
    SBARRIER();
    // P8: stage (t+3).A0 -> buf1; drain all but newest stage
    STAGE(Ap, lda, ktn2, 1, 0, 0);
    SBARRIER(); WAIT_LGKM0();
    __builtin_amdgcn_s_setprio(1); MFMA16(4, 1); __builtin_amdgcn_s_setprio(0);
    WAIT_VM2();
    SBARRIER();
  }

  // Epilogue: C/D layout col=lane&15, row=(lane>>4)*4+r (m89-verified)
  const int rowQ = (lane >> 4) * 4;
#pragma unroll
  for (int ni = 0; ni < 4; ni++) {
    const int col = (int)colBase + wn * 64 + ni * 16 + fr;
    const float bv = bias[col];
    const bool doRelu = col < relu_lim;
#pragma unroll
    for (int mi = 0; mi < 8; mi++) {
      const long row = rowBase + wm * 128 + mi * 16 + rowQ;
#pragma unroll
      for (int r = 0; r < 4; r++) {
        float v = acc[mi][ni][r] + bv;
        if (doRelu) v = fmaxf(v, 0.f);
        if (OUT_F32)
          ((float*)Cout)[z * strideC + (row + r) * (long)ldc + col] = v;
        else
          ((ushort_t*)Cout)[z * strideC + (row + r) * (long)ldc + col] = f2bf(v);
      }
    }
  }
#undef SLOT
#undef STAGE
#undef LOADA
#undef LOADB
#undef MFMA16
}

// ---------------- KV state partials ----------------
__global__ __launch_bounds__(64) void k_kv_partial(const ushort_t* __restrict__ qkv,
                                                   float* __restrict__ partial) {
  const int bh = blockIdx.x;
  const int chunk = blockIdx.y;
  const int b = bh >> 4, h = bh & 15;
  const int t = threadIdx.x;
  const int d0 = (t >> 2) * 4;
  const int e0 = (t & 3) * 16;
  __shared__ float kk[16][64];
  __shared__ float vv[16][64];
  float acc[4][16];
#pragma unroll
  for (int di = 0; di < 4; di++)
#pragma unroll
    for (int j = 0; j < 16; j++) acc[di][j] = 0.f;

  const long rowbase = (long)b * 4096 + (long)chunk * 128;
  for (int it = 0; it < 8; it++) {
    __syncthreads();
#pragma unroll
    for (int rep = 0; rep < 4; rep++) {
      int idx = rep * 64 + t;
      int row = idx >> 4, c4 = (idx & 15) * 4;
      long m = rowbase + it * 16 + row;
      ushort4 kr = *reinterpret_cast<const ushort4*>(&qkv[m * 3072 + 1024 + h * 64 + c4]);
      ushort4 vr = *reinterpret_cast<const ushort4*>(&qkv[m * 3072 + 2048 + h * 64 + c4]);
      float4 kf = make_float4(bf2f(kr.x), bf2f(kr.y), bf2f(kr.z), bf2f(kr.w));
      float4 vf = make_float4(bf2f(vr.x), bf2f(vr.y), bf2f(vr.z), bf2f(vr.w));
      *reinterpret_cast<float4*>(&kk[row][c4]) = kf;
      *reinterpret_cast<float4*>(&vv[row][c4]) = vf;
    }
    __syncthreads();
#pragma unroll
    for (int ss = 0; ss < 16; ss++) {
      const float4 kq = *reinterpret_cast<const float4*>(&kk[ss][d0]);
#pragma unroll
      for (int jj = 0; jj < 4; jj++) {
        const float4 vq = *reinterpret_cast<const float4*>(&vv[ss][e0 + jj * 4]);
        acc[0][jj * 4 + 0] = fmaf(kq.x, vq.x, acc[0][jj * 4 + 0]);
        acc[0][jj * 4 + 1] = fmaf(kq.x, vq.y, acc[0][jj * 4 + 1]);
        acc[0][jj * 4 + 2] = fmaf(kq.x, vq.z, acc[0][jj * 4 + 2]);
        acc[0][jj * 4 + 3] = fmaf(kq.x, vq.w, acc[0][jj * 4 + 3]);
        acc[1][jj * 4 + 0] = fmaf(kq.y, vq.x, acc[1][jj * 4 + 0]);
        acc[1][jj * 4 + 1] = fmaf(kq.y, vq.y, acc[1][jj * 4 + 1]);
        acc[1][jj * 4 + 2] = fmaf(kq.y, vq.z, acc[1][jj * 4 + 2]);
        acc[1][jj * 4 + 3] = fmaf(kq.y, vq.w, acc[1][jj * 4 + 3]);
        acc[2][jj * 4 + 0] = fmaf(kq.z, vq.x, acc[2][jj * 4 + 0]);
        acc[2][jj * 4 + 1] = fmaf(kq.z, vq.y, acc[2][jj * 4 + 1]);
        acc[2][jj * 4 + 2] = fmaf(kq.z, vq.z, acc[2][jj * 4 + 2]);
        acc[2][jj * 4 + 3] = fmaf(kq.z, vq.w, acc[2][jj * 4 + 3]);
        acc[3][jj * 4 + 0] = fmaf(kq.w, vq.x, acc[3][jj * 4 + 0]);
        acc[3][jj * 4 + 1] = fmaf(kq.w, vq.y, acc[3][jj * 4 + 1]);
        acc[3][jj * 4 + 2] = fmaf(kq.w, vq.z, acc[3][jj * 4 + 2]);
        acc[3][jj * 4 + 3] = fmaf(kq.w, vq.w, acc[3][jj * 4 + 3]);
      }
    }
  }
  float* dst = partial + ((long)chunk * 64 + bh) * 4096;
#pragma unroll
  for (int di = 0; di < 4; di++)
#pragma unroll
    for (int jj = 0; jj < 4; jj++) {
      float4 o = make_float4(acc[di][jj * 4], acc[di][jj * 4 + 1], acc[di][jj * 4 + 2],
                             acc[di][jj * 4 + 3]);
      *reinterpret_cast<float4*>(&dst[(d0 + di) * 64 + e0 + jj * 4]) = o;
    }
}

__global__ __launch_bounds__(256) void k_kv_reduce(const float* __restrict__ partial,
                                                   float* __restrict__ kv) {
  int i4 = (blockIdx.x * 256 + threadIdx.x) * 4;
  float4 s = make_float4(0.f, 0.f, 0.f, 0.f);
#pragma unroll
  for (int c = 0; c < 32; c++) {
    float4 p = *reinterpret_cast<const float4*>(&partial[(long)c * 262144 + i4]);
    s.x += p.x; s.y += p.y; s.z += p.z; s.w += p.w;
  }
  *reinterpret_cast<float4*>(&kv[i4]) = s;
}

// ---------------- fused weight: FW_b[n][h*64+d] = sum_e kv[b,h][d][e] * ow[n][h*64+e]
__global__ __launch_bounds__(256) void k_fuse_w(const float* __restrict__ kv,
                                                const ushort_t* __restrict__ ow,
                                                ushort_t* __restrict__ qkv) {
  const int nt = blockIdx.x;
  const int h = blockIdx.y;
  const int b = blockIdx.z;
  const int t = threadIdx.x;
  const int nn = t >> 2;
  const int d0 = (t & 3) * 16;
  __shared__ float kvt[64][68];
  __shared__ ushort_t ows[64][68];
  const float* kvsrc = kv + (long)(b * 16 + h) * 4096;
  const int n0 = nt * 64;
#pragma unroll
  for (int rep = 0; rep < 16; rep++) {
    int lin = rep * 256 + t;
    int d = lin >> 6, e = lin & 63;
    kvt[e][d] = kvsrc[d * 64 + e];
  }
#pragma unroll
  for (int rep = 0; rep < 4; rep++) {
    int lin = rep * 256 + t;
    int r = lin >> 4, c4 = (lin & 15) * 4;
    *reinterpret_cast<ushort4*>(&ows[r][c4]) =
        *reinterpret_cast<const ushort4*>(&ow[(long)(n0 + r) * 1024 + h * 64 + c4]);
  }
  __syncthreads();
  float acc[16];
#pragma unroll
  for (int j = 0; j < 16; j++) acc[j] = 0.f;
  for (int e = 0; e < 64; e++) {
    float own = bf2f(ows[nn][e]);
#pragma unroll
    for (int jj = 0; jj < 4; jj++) {
      const float4 kq = *reinterpret_cast<const float4*>(&kvt[e][d0 + jj * 4]);
      acc[jj * 4 + 0] = fmaf(own, kq.x, acc[jj * 4 + 0]);
      acc[jj * 4 + 1] = fmaf(own, kq.y, acc[jj * 4 + 1]);
      acc[jj * 4 + 2] = fmaf(own, kq.z, acc[jj * 4 + 2]);
      acc[jj * 4 + 3] = fmaf(own, kq.w, acc[jj * 4 + 3]);
    }
  }
  ushort_t* dst = qkv + (long)(b * 1024 + n0 + nn) * 3072 + 1024 + h * 64 + d0;
#pragma unroll
  for (int jj = 0; jj < 4; jj++) {
    ushort4 o;
    o.x = f2bf(acc[jj * 4 + 0]); o.y = f2bf(acc[jj * 4 + 1]);
    o.z = f2bf(acc[jj * 4 + 2]); o.w = f2bf(acc[jj * 4 + 3]);
    *reinterpret_cast<ushort4*>(dst + jj * 4) = o;
  }
}

extern "C" void kernel_launch(void* const* d_in, const int* in_sizes, int n_in, void* d_out,
                              int out_size, void* d_ws, size_t ws_size, hipStream_t stream) {
  const float* x   = (const float*)d_in[0];
  const float* q_w = (const float*)d_in[1];
  const float* q_b = (const float*)d_in[2];
  const float* k_w = (const float*)d_in[3];
  const float* k_b = (const float*)d_in[4];
  const float* v_w = (const float*)d_in[5];
  const float* v_b = (const float*)d_in[6];
  const float* o_w = (const float*)d_in[7];
  const float* o_b = (const float*)d_in[8];
  float* out = (float*)d_out;

  const int D = 1024, M = 16384;
  char* ws = (char*)d_ws;
  ushort_t* xb    = (ushort_t*)(ws);              // 33,554,432  x as bf16
  ushort_t* wqkv  = (ushort_t*)(ws + 33554432);   //  6,291,456  [q_w;k_w;v_w] bf16
  ushort_t* owb   = (ushort_t*)(ws + 39845888);   //  2,097,152  o_w bf16
  float*    biasq = (float*)(ws + 41943040);      //     12,288  [q_b;k_b;v_b]
  ushort_t* qkv   = (ushort_t*)(ws + 41955328);   // 100,663,296 [M][3072] bf16
  float* partial = (float*)(ws);                  // 33,554,432  [32][64][4096] (recycles xb)
  float* kvbuf   = (float*)(ws + 33554432);       //  1,048,576  (recycles wqkv)

  k_f32_to_bf16<<<16384, 256, 0, stream>>>(x, xb, M * D);
  k_pack_w4<<<4096, 256, 0, stream>>>(q_w, k_w, v_w, o_w, wqkv);
  hipMemcpyAsync(biasq, q_b, D * sizeof(float), hipMemcpyDeviceToDevice, stream);
  hipMemcpyAsync(biasq + D, k_b, D * sizeof(float), hipMemcpyDeviceToDevice, stream);
  hipMemcpyAsync(biasq + 2 * D, v_b, D * sizeof(float), hipMemcpyDeviceToDevice, stream);

  // QKV projection: [16384 x 1024] x [3072 x 1024]^T (+bias, relu on cols<2048)
  k_gemm256<false><<<dim3(12, 64, 1), 512, 0, stream>>>(xb, 1024, 0, wqkv, 1024, 0,
                                                        biasq, 2048, qkv, 3072, 0, 1024);
  // KV state
  k_kv_partial<<<dim3(64, 32), 64, 0, stream>>>(qkv, partial);
  k_kv_reduce<<<256, 256, 0, stream>>>(partial, kvbuf);
  // fold KV into o_w (per-batch fused weight in dead k-columns of qkv rows 0..4095)
  k_fuse_w<<<dim3(16, 16, 4), 256, 0, stream>>>(kvbuf, owb, qkv);
  // out_b = relu(q)_b @ FW_b^T + o_b  — single batched launch (grid.z = 4)
  k_gemm256<true><<<dim3(4, 16, 4), 512, 0, stream>>>(
      qkv, 3072, (long)4096 * 3072, qkv + 1024, 3072, (long)1024 * 3072,
      o_b, 0, out, 1024, (long)4096 * 1024, 1024);
}